// Round 1
// baseline (579.280 us; speedup 1.0000x reference)
//
#include <hip/hip_runtime.h>

#define BB 4
#define TT 2048
#define CC 1024
#define HH 16
#define DD 64
#define WIN 256

typedef __attribute__((ext_vector_type(8))) short short8;
typedef __attribute__((ext_vector_type(4))) float floatx4;
typedef unsigned short u16;

__device__ __forceinline__ float bf2f(u16 u) {
    union { unsigned int i; float f; } v; v.i = ((unsigned int)u) << 16; return v.f;
}
__device__ __forceinline__ u16 f2bf(float f) {
    union { float f; unsigned int i; } v; v.f = f;
    unsigned int x = v.i;
    x += ((x >> 16) & 1u) + 0x7FFFu;   // round-to-nearest-even
    return (u16)(x >> 16);
}

// ---------------- fp32 -> bf16 conversion ----------------
__global__ void cvt_f32_bf16(const float* __restrict__ in, u16* __restrict__ out, int n) {
    int i = (blockIdx.x * 256 + threadIdx.x) * 8;
    if (i >= n) return;
    float4 a = *(const float4*)(in + i);
    float4 b = *(const float4*)(in + i + 4);
    u16 o[8] = { f2bf(a.x), f2bf(a.y), f2bf(a.z), f2bf(a.w),
                 f2bf(b.x), f2bf(b.y), f2bf(b.z), f2bf(b.w) };
    *(uint4*)(out + i) = *(const uint4*)o;
}

// ---------------- bf16 MFMA GEMM: C = A @ B^T (+bias), QKV scatter epilogue ----
// A: [8192,1024] bf16 row-major, Bw: [3072,1024] bf16 row-major
__global__ __launch_bounds__(256) void gemm_qkv(
    const u16* __restrict__ A, const u16* __restrict__ Bw,
    const float* __restrict__ bias,
    u16* __restrict__ Qb, u16* __restrict__ Kb, u16* __restrict__ Vb)
{
    const int K = CC;
    __shared__ u16 As[128][40];  // pad 8 -> 80B row stride, keeps 16B align
    __shared__ u16 Bs[128][40];
    const int tid = threadIdx.x;
    const int wave = tid >> 6, lane = tid & 63;
    const int wm = wave >> 1, wn = wave & 1;
    const int quad = lane >> 4, l15 = lane & 15;
    const int bN = blockIdx.x * 128, bM = blockIdx.y * 128;

    floatx4 acc[4][4] = {};

    for (int k0 = 0; k0 < K; k0 += 32) {
        __syncthreads();
#pragma unroll
        for (int it = 0; it < 2; ++it) {
            int slot = tid + it * 256;
            int r = slot >> 2;
            int c8 = (slot & 3) << 3;
            *(uint4*)&As[r][c8] = *(const uint4*)&A[(size_t)(bM + r) * K + k0 + c8];
            *(uint4*)&Bs[r][c8] = *(const uint4*)&Bw[(size_t)(bN + r) * K + k0 + c8];
        }
        __syncthreads();
        short8 af[4], bf[4];
#pragma unroll
        for (int i = 0; i < 4; ++i) {
            af[i] = *(const short8*)&As[wm * 64 + i * 16 + l15][quad * 8];
            bf[i] = *(const short8*)&Bs[wn * 64 + i * 16 + l15][quad * 8];
        }
#pragma unroll
        for (int mi = 0; mi < 4; ++mi)
#pragma unroll
            for (int ni = 0; ni < 4; ++ni)
                acc[mi][ni] = __builtin_amdgcn_mfma_f32_16x16x32_bf16(af[mi], bf[ni], acc[mi][ni], 0, 0, 0);
    }

#pragma unroll
    for (int mi = 0; mi < 4; ++mi)
#pragma unroll
        for (int ni = 0; ni < 4; ++ni) {
            int col = bN + wn * 64 + ni * 16 + l15;          // 0..3071
            float bv = bias[col];
            int which = col >> 10, rem = col & 1023;
            int h = rem >> 6, d = rem & 63;
            u16* dst = which == 0 ? Qb : (which == 1 ? Kb : Vb);
#pragma unroll
            for (int rg = 0; rg < 4; ++rg) {
                int row = bM + wm * 64 + mi * 16 + quad * 4 + rg;  // 0..8191
                int b = row >> 11, t = row & 2047;
                float v = acc[mi][ni][rg] + bv;
                dst[(((size_t)(b * HH + h)) * TT + t) * DD + d] = f2bf(v);
            }
        }
}

// ---------------- bf16 MFMA GEMM: Out = A @ B^T + bias (fp32 out) ------------
__global__ __launch_bounds__(256) void gemm_proj(
    const u16* __restrict__ A, const u16* __restrict__ Bw,
    const float* __restrict__ bias, float* __restrict__ Out)
{
    const int K = CC;
    __shared__ u16 As[128][40];
    __shared__ u16 Bs[128][40];
    const int tid = threadIdx.x;
    const int wave = tid >> 6, lane = tid & 63;
    const int wm = wave >> 1, wn = wave & 1;
    const int quad = lane >> 4, l15 = lane & 15;
    const int bN = blockIdx.x * 128, bM = blockIdx.y * 128;

    floatx4 acc[4][4] = {};

    for (int k0 = 0; k0 < K; k0 += 32) {
        __syncthreads();
#pragma unroll
        for (int it = 0; it < 2; ++it) {
            int slot = tid + it * 256;
            int r = slot >> 2;
            int c8 = (slot & 3) << 3;
            *(uint4*)&As[r][c8] = *(const uint4*)&A[(size_t)(bM + r) * K + k0 + c8];
            *(uint4*)&Bs[r][c8] = *(const uint4*)&Bw[(size_t)(bN + r) * K + k0 + c8];
        }
        __syncthreads();
        short8 af[4], bf[4];
#pragma unroll
        for (int i = 0; i < 4; ++i) {
            af[i] = *(const short8*)&As[wm * 64 + i * 16 + l15][quad * 8];
            bf[i] = *(const short8*)&Bs[wn * 64 + i * 16 + l15][quad * 8];
        }
#pragma unroll
        for (int mi = 0; mi < 4; ++mi)
#pragma unroll
            for (int ni = 0; ni < 4; ++ni)
                acc[mi][ni] = __builtin_amdgcn_mfma_f32_16x16x32_bf16(af[mi], bf[ni], acc[mi][ni], 0, 0, 0);
    }

#pragma unroll
    for (int mi = 0; mi < 4; ++mi)
#pragma unroll
        for (int ni = 0; ni < 4; ++ni) {
            int col = bN + wn * 64 + ni * 16 + l15;
            float bv = bias[col];
#pragma unroll
            for (int rg = 0; rg < 4; ++rg) {
                int row = bM + wm * 64 + mi * 16 + quad * 4 + rg;
                Out[(size_t)row * CC + col] = acc[mi][ni][rg] + bv;
            }
        }
}

// ---------------- windowed causal attention (fp32 VALU, 2-pass) --------------
// Q/K/V: [B*H, T, D] bf16.  Y: [B, T, C] bf16 (already transposed for proj GEMM)
__global__ __launch_bounds__(256) void attn(
    const u16* __restrict__ Qb, const u16* __restrict__ Kb, const u16* __restrict__ Vb,
    u16* __restrict__ Y)
{
    __shared__ float Qs[32][68];
    __shared__ float KVs[32][68];
    __shared__ float S[32][289];

    const int tid = threadIdx.x;
    const int q0 = blockIdx.x * 32;
    const int bh = blockIdx.y;
    const int b = bh >> 4, h = bh & 15;
    const u16* Qp = Qb + (size_t)bh * TT * DD;
    const u16* Kp = Kb + (size_t)bh * TT * DD;
    const u16* Vp = Vb + (size_t)bh * TT * DD;

    const int kb = (q0 > WIN - 1) ? (q0 - (WIN - 1)) : 0;   // first key index
    const int nk = q0 + 32 - kb;                            // #keys (<=287)
    const int nc = (nk + 31) >> 5;                          // key chunks of 32
    const int kend = q0 + 32;

    // load Q tile (32 rows x 64), bf16 -> f32
    {
        int rq = tid >> 3, d8 = (tid & 7) << 3;
        uint4 raw = *(const uint4*)&Qp[(q0 + rq) * DD + d8];
        const u16* u = (const u16*)&raw;
#pragma unroll
        for (int i = 0; i < 8; ++i) Qs[rq][d8 + i] = bf2f(u[i]);
    }

    const int r = tid >> 3;   // query row owned by this thread (0..31)
    const int g = tid & 7;    // sub-group index (0..7)
    const float scale = 0.125f;  // 1/sqrt(64)

    // ---- phase 1: scores S[32][nc*32] ----
    for (int c = 0; c < nc; ++c) {
        int j0 = kb + c * 32;
        __syncthreads();
        {
            int jj = tid >> 3, d8 = (tid & 7) << 3;
            int j = j0 + jj;
            if (j < kend) {
                uint4 raw = *(const uint4*)&Kp[j * DD + d8];
                const u16* u = (const u16*)&raw;
#pragma unroll
                for (int i = 0; i < 8; ++i) KVs[jj][d8 + i] = bf2f(u[i]);
            } else {
#pragma unroll
                for (int i = 0; i < 8; ++i) KVs[jj][d8 + i] = 0.f;
            }
        }
        __syncthreads();
        int jj0 = g << 2;   // this thread: row r, key cols jj0..jj0+3
        float s0 = 0.f, s1 = 0.f, s2 = 0.f, s3 = 0.f;
#pragma unroll
        for (int kk = 0; kk < 16; ++kk) {
            float4 q  = *(const float4*)&Qs[r][kk * 4];
            float4 k0 = *(const float4*)&KVs[jj0 + 0][kk * 4];
            float4 k1 = *(const float4*)&KVs[jj0 + 1][kk * 4];
            float4 k2 = *(const float4*)&KVs[jj0 + 2][kk * 4];
            float4 k3 = *(const float4*)&KVs[jj0 + 3][kk * 4];
            s0 += q.x * k0.x + q.y * k0.y + q.z * k0.z + q.w * k0.w;
            s1 += q.x * k1.x + q.y * k1.y + q.z * k1.z + q.w * k1.w;
            s2 += q.x * k2.x + q.y * k2.y + q.z * k2.z + q.w * k2.w;
            s3 += q.x * k3.x + q.y * k3.y + q.z * k3.z + q.w * k3.w;
        }
        float ss[4] = { s0, s1, s2, s3 };
        int qi = q0 + r;
#pragma unroll
        for (int i = 0; i < 4; ++i) {
            int j = j0 + jj0 + i;
            bool valid = (j <= qi) && (qi - j < WIN);
            S[r][c * 32 + jj0 + i] = valid ? ss[i] * scale : -1e30f;
        }
    }
    __syncthreads();

    // ---- phase 2: softmax per row (8 threads per row, shuffle-reduce) ----
    const int ncol = nc << 5;
    float mx = -1e30f;
    for (int col = g; col < ncol; col += 8) mx = fmaxf(mx, S[r][col]);
#pragma unroll
    for (int m = 1; m < 8; m <<= 1) mx = fmaxf(mx, __shfl_xor(mx, m, 64));
    float sum = 0.f;
    for (int col = g; col < ncol; col += 8) {
        float e = __expf(S[r][col] - mx);
        S[r][col] = e;
        sum += e;
    }
#pragma unroll
    for (int m = 1; m < 8; m <<= 1) sum += __shfl_xor(sum, m, 64);
    float inv = 1.f / sum;
    for (int col = g; col < ncol; col += 8) S[r][col] *= inv;

    // ---- phase 3: O = P @ V ----
    float oa[8] = {0.f, 0.f, 0.f, 0.f, 0.f, 0.f, 0.f, 0.f};
    const int d0 = g << 3;
    for (int c = 0; c < nc; ++c) {
        int j0 = kb + c * 32;
        __syncthreads();
        {
            int jj = tid >> 3, d8 = (tid & 7) << 3;
            int j = j0 + jj;
            if (j < kend) {
                uint4 raw = *(const uint4*)&Vp[j * DD + d8];
                const u16* u = (const u16*)&raw;
#pragma unroll
                for (int i = 0; i < 8; ++i) KVs[jj][d8 + i] = bf2f(u[i]);
            } else {
#pragma unroll
                for (int i = 0; i < 8; ++i) KVs[jj][d8 + i] = 0.f;
            }
        }
        __syncthreads();
#pragma unroll 4
        for (int jj = 0; jj < 32; ++jj) {
            float p = S[r][c * 32 + jj];
            float4 v0 = *(const float4*)&KVs[jj][d0];
            float4 v1 = *(const float4*)&KVs[jj][d0 + 4];
            oa[0] += p * v0.x; oa[1] += p * v0.y; oa[2] += p * v0.z; oa[3] += p * v0.w;
            oa[4] += p * v1.x; oa[5] += p * v1.y; oa[6] += p * v1.z; oa[7] += p * v1.w;
        }
    }
    // write Y[b, t, h*64 + d0 .. +7] as bf16
    int t = q0 + r;
    u16 o[8];
#pragma unroll
    for (int i = 0; i < 8; ++i) o[i] = f2bf(oa[i]);
    *(uint4*)&Y[((size_t)b * TT + t) * CC + h * DD + d0] = *(const uint4*)o;
}

// ---------------- launch ----------------
extern "C" void kernel_launch(void* const* d_in, const int* in_sizes, int n_in,
                              void* d_out, int out_size, void* d_ws, size_t ws_size,
                              hipStream_t stream) {
    const float* x      = (const float*)d_in[0];
    // d_in[1] = attn_mask (bool) — mask structure is analytic, unused
    const float* qkv_w  = (const float*)d_in[2];
    const float* qkv_b  = (const float*)d_in[3];
    const float* proj_w = (const float*)d_in[4];
    const float* proj_b = (const float*)d_in[5];
    float* out = (float*)d_out;

    u16* xb  = (u16*)d_ws;                         // 8192*1024
    u16* wb  = xb  + (size_t)8192 * 1024;          // 3072*1024
    u16* pwb = wb  + (size_t)3072 * 1024;          // 1024*1024
    u16* Qb  = pwb + (size_t)1024 * 1024;          // 64*2048*64
    u16* Kb  = Qb  + (size_t)64 * 2048 * 64;
    u16* Vb  = Kb  + (size_t)64 * 2048 * 64;
    u16* Yb  = Vb  + (size_t)64 * 2048 * 64;       // 8192*1024

    cvt_f32_bf16<<<4096, 256, 0, stream>>>(x, xb, 8192 * 1024);
    cvt_f32_bf16<<<1536, 256, 0, stream>>>(qkv_w, wb, 3072 * 1024);
    cvt_f32_bf16<<<512, 256, 0, stream>>>(proj_w, pwb, 1024 * 1024);

    gemm_qkv<<<dim3(24, 64), 256, 0, stream>>>(xb, wb, qkv_b, Qb, Kb, Vb);
    attn<<<dim3(TT / 32, BB * HH), 256, 0, stream>>>(Qb, Kb, Vb, Yb);
    gemm_proj<<<dim3(8, 64), 256, 0, stream>>>(Yb, pwb, proj_b, out);
}

// Round 2
// 273.416 us; speedup vs baseline: 2.1187x; 2.1187x over previous
//
#include <hip/hip_runtime.h>

#define BB 4
#define TT 2048
#define CC 1024
#define HH 16
#define DD 64
#define WIN 256

typedef __attribute__((ext_vector_type(8))) short short8;
typedef __attribute__((ext_vector_type(4))) float floatx4;
typedef unsigned short u16;

__device__ __forceinline__ float bf2f(u16 u) {
    union { unsigned int i; float f; } v; v.i = ((unsigned int)u) << 16; return v.f;
}
__device__ __forceinline__ u16 f2bf(float f) {
    union { float f; unsigned int i; } v; v.f = f;
    unsigned int x = v.i;
    x += ((x >> 16) & 1u) + 0x7FFFu;   // round-to-nearest-even
    return (u16)(x >> 16);
}

// ---------------- fp32 -> bf16 conversion ----------------
__global__ void cvt_f32_bf16(const float* __restrict__ in, u16* __restrict__ out, int n) {
    int i = (blockIdx.x * 256 + threadIdx.x) * 8;
    if (i >= n) return;
    float4 a = *(const float4*)(in + i);
    float4 b = *(const float4*)(in + i + 4);
    u16 o[8] = { f2bf(a.x), f2bf(a.y), f2bf(a.z), f2bf(a.w),
                 f2bf(b.x), f2bf(b.y), f2bf(b.z), f2bf(b.w) };
    *(uint4*)(out + i) = *(const uint4*)o;
}

// ---------------- bf16 MFMA GEMM: C = A @ B^T (+bias), QKV scatter epilogue ----
// A: [8192,1024] bf16 row-major, Bw: [3072,1024] bf16 row-major
__global__ __launch_bounds__(256) void gemm_qkv(
    const u16* __restrict__ A, const u16* __restrict__ Bw,
    const float* __restrict__ bias,
    u16* __restrict__ Qb, u16* __restrict__ Kb, u16* __restrict__ Vb)
{
    const int K = CC;
    __shared__ u16 As[128][40];  // pad 8 -> 80B row stride, keeps 16B align
    __shared__ u16 Bs[128][40];
    const int tid = threadIdx.x;
    const int wave = tid >> 6, lane = tid & 63;
    const int wm = wave >> 1, wn = wave & 1;
    const int quad = lane >> 4, l15 = lane & 15;
    const int bN = blockIdx.x * 128, bM = blockIdx.y * 128;

    floatx4 acc[4][4] = {};

    for (int k0 = 0; k0 < K; k0 += 32) {
        __syncthreads();
#pragma unroll
        for (int it = 0; it < 2; ++it) {
            int slot = tid + it * 256;
            int r = slot >> 2;
            int c8 = (slot & 3) << 3;
            *(uint4*)&As[r][c8] = *(const uint4*)&A[(size_t)(bM + r) * K + k0 + c8];
            *(uint4*)&Bs[r][c8] = *(const uint4*)&Bw[(size_t)(bN + r) * K + k0 + c8];
        }
        __syncthreads();
        short8 af[4], bf[4];
#pragma unroll
        for (int i = 0; i < 4; ++i) {
            af[i] = *(const short8*)&As[wm * 64 + i * 16 + l15][quad * 8];
            bf[i] = *(const short8*)&Bs[wn * 64 + i * 16 + l15][quad * 8];
        }
#pragma unroll
        for (int mi = 0; mi < 4; ++mi)
#pragma unroll
            for (int ni = 0; ni < 4; ++ni)
                acc[mi][ni] = __builtin_amdgcn_mfma_f32_16x16x32_bf16(af[mi], bf[ni], acc[mi][ni], 0, 0, 0);
    }

#pragma unroll
    for (int mi = 0; mi < 4; ++mi)
#pragma unroll
        for (int ni = 0; ni < 4; ++ni) {
            int col = bN + wn * 64 + ni * 16 + l15;          // 0..3071
            float bv = bias[col];
            int which = col >> 10, rem = col & 1023;
            int h = rem >> 6, d = rem & 63;
            u16* dst = which == 0 ? Qb : (which == 1 ? Kb : Vb);
#pragma unroll
            for (int rg = 0; rg < 4; ++rg) {
                int row = bM + wm * 64 + mi * 16 + quad * 4 + rg;  // 0..8191
                int b = row >> 11, t = row & 2047;
                float v = acc[mi][ni][rg] + bv;
                dst[(((size_t)(b * HH + h)) * TT + t) * DD + d] = f2bf(v);
            }
        }
}

// ---------------- bf16 MFMA GEMM: Out = A @ B^T + bias (fp32 out) ------------
__global__ __launch_bounds__(256) void gemm_proj(
    const u16* __restrict__ A, const u16* __restrict__ Bw,
    const float* __restrict__ bias, float* __restrict__ Out)
{
    const int K = CC;
    __shared__ u16 As[128][40];
    __shared__ u16 Bs[128][40];
    const int tid = threadIdx.x;
    const int wave = tid >> 6, lane = tid & 63;
    const int wm = wave >> 1, wn = wave & 1;
    const int quad = lane >> 4, l15 = lane & 15;
    const int bN = blockIdx.x * 128, bM = blockIdx.y * 128;

    floatx4 acc[4][4] = {};

    for (int k0 = 0; k0 < K; k0 += 32) {
        __syncthreads();
#pragma unroll
        for (int it = 0; it < 2; ++it) {
            int slot = tid + it * 256;
            int r = slot >> 2;
            int c8 = (slot & 3) << 3;
            *(uint4*)&As[r][c8] = *(const uint4*)&A[(size_t)(bM + r) * K + k0 + c8];
            *(uint4*)&Bs[r][c8] = *(const uint4*)&Bw[(size_t)(bN + r) * K + k0 + c8];
        }
        __syncthreads();
        short8 af[4], bf[4];
#pragma unroll
        for (int i = 0; i < 4; ++i) {
            af[i] = *(const short8*)&As[wm * 64 + i * 16 + l15][quad * 8];
            bf[i] = *(const short8*)&Bs[wn * 64 + i * 16 + l15][quad * 8];
        }
#pragma unroll
        for (int mi = 0; mi < 4; ++mi)
#pragma unroll
            for (int ni = 0; ni < 4; ++ni)
                acc[mi][ni] = __builtin_amdgcn_mfma_f32_16x16x32_bf16(af[mi], bf[ni], acc[mi][ni], 0, 0, 0);
    }

#pragma unroll
    for (int mi = 0; mi < 4; ++mi)
#pragma unroll
        for (int ni = 0; ni < 4; ++ni) {
            int col = bN + wn * 64 + ni * 16 + l15;
            float bv = bias[col];
#pragma unroll
            for (int rg = 0; rg < 4; ++rg) {
                int row = bM + wm * 64 + mi * 16 + quad * 4 + rg;
                Out[(size_t)row * CC + col] = acc[mi][ni][rg] + bv;
            }
        }
}

// ---------------- flash attention, MFMA (bf16 in, fp32 acc) ------------------
// Q/K/V: [B*H, T, D] bf16.  Y: [B, T, C] bf16 (transposed for proj GEMM)
// Block: 256 threads = 4 waves; 64 queries/block (16/wave); key chunks of 64.
__global__ __launch_bounds__(256) void attn_mfma(
    const u16* __restrict__ Qb, const u16* __restrict__ Kb, const u16* __restrict__ Vb,
    u16* __restrict__ Y)
{
    __shared__ u16 Ks[64][72];        // K chunk, [j][d], +8 pad
    __shared__ u16 Vt[64][72];        // V chunk transposed [d][j], XOR-swizzled j-blocks
    __shared__ u16 Ps[4][16][72];     // per-wave P round-trip buffer [q][j]

    const int tid = threadIdx.x;
    const int wave = tid >> 6, lane = tid & 63;
    const int quad = lane >> 4, l15 = lane & 15;
    const int q0 = blockIdx.x * 64;
    const int bh = blockIdx.y;
    const int b = bh >> 4, h = bh & 15;
    const u16* Qp = Qb + (size_t)bh * TT * DD;
    const u16* Kp = Kb + (size_t)bh * TT * DD;
    const u16* Vp = Vb + (size_t)bh * TT * DD;
    const int qw = q0 + wave * 16;    // this wave's first query

    // Q A-fragments: m=l15 (query), k=quad*8+j (d), 2 k-steps
    short8 qf[2];
    qf[0] = *(const short8*)&Qp[(size_t)(qw + l15) * DD + quad * 8];
    qf[1] = *(const short8*)&Qp[(size_t)(qw + l15) * DD + 32 + quad * 8];

    float m_i[4] = { -1e30f, -1e30f, -1e30f, -1e30f };
    float l_i[4] = { 0.f, 0.f, 0.f, 0.f };
    floatx4 Oacc[4] = {};             // [dtile]; C layout: row=quad*4+reg, col(d)=dt*16+l15

    const int kb = (q0 >= WIN) ? (q0 - WIN) : 0;
    for (int j0 = kb; j0 < q0 + 64; j0 += 64) {
        __syncthreads();
        // stage K chunk [j][d], vectorized
#pragma unroll
        for (int it = 0; it < 2; ++it) {
            int slot = tid + it * 256;
            int j = slot >> 3, c8 = (slot & 7) << 3;
            *(uint4*)&Ks[j][c8] = *(const uint4*)&Kp[(size_t)(j0 + j) * DD + c8];
        }
        // stage V transposed [d][j], swizzle j-block by d>>3 (conflict-free writes)
#pragma unroll
        for (int it = 0; it < 2; ++it) {
            int slot = tid + it * 256;
            int j = slot >> 3, d0 = (slot & 7) << 3;
            uint4 raw = *(const uint4*)&Vp[(size_t)(j0 + j) * DD + d0];
            const u16* u = (const u16*)&raw;
#pragma unroll
            for (int i = 0; i < 8; ++i) {
                int d = d0 + i;
                int col = (((j >> 3) ^ (d >> 3)) << 3) + (j & 7);
                Vt[d][col] = u[i];
            }
        }
        __syncthreads();

        // ---- S = Q K^T (scaled), 4 n-tiles of 16 keys ----
        floatx4 Sacc[4] = {};
#pragma unroll
        for (int nt = 0; nt < 4; ++nt) {
            short8 kf0 = *(const short8*)&Ks[nt * 16 + l15][quad * 8];
            short8 kf1 = *(const short8*)&Ks[nt * 16 + l15][32 + quad * 8];
            Sacc[nt] = __builtin_amdgcn_mfma_f32_16x16x32_bf16(qf[0], kf0, Sacc[nt], 0, 0, 0);
            Sacc[nt] = __builtin_amdgcn_mfma_f32_16x16x32_bf16(qf[1], kf1, Sacc[nt], 0, 0, 0);
        }

        // ---- mask + scale + chunk row-max ----
        float mc[4] = { -1e30f, -1e30f, -1e30f, -1e30f };
#pragma unroll
        for (int nt = 0; nt < 4; ++nt)
#pragma unroll
            for (int r = 0; r < 4; ++r) {
                int q = qw + quad * 4 + r;
                int j = j0 + nt * 16 + l15;
                float s = (j <= q && (q - j) < WIN) ? Sacc[nt][r] * 0.125f : -1e30f;
                Sacc[nt][r] = s;
                mc[r] = fmaxf(mc[r], s);
            }
#pragma unroll
        for (int m = 1; m < 16; m <<= 1)
#pragma unroll
            for (int r = 0; r < 4; ++r) mc[r] = fmaxf(mc[r], __shfl_xor(mc[r], m, 64));

        // ---- online softmax update ----
        float alpha[4];
#pragma unroll
        for (int r = 0; r < 4; ++r) {
            float mn = fmaxf(m_i[r], mc[r]);
            alpha[r] = __expf(m_i[r] - mn);
            m_i[r] = mn;
        }
        float rs[4] = { 0.f, 0.f, 0.f, 0.f };
#pragma unroll
        for (int nt = 0; nt < 4; ++nt)
#pragma unroll
            for (int r = 0; r < 4; ++r) {
                float s = Sacc[nt][r];
                float p = (s > -1e29f) ? __expf(s - m_i[r]) : 0.f;
                Sacc[nt][r] = p;
                rs[r] += p;
            }
#pragma unroll
        for (int m = 1; m < 16; m <<= 1)
#pragma unroll
            for (int r = 0; r < 4; ++r) rs[r] += __shfl_xor(rs[r], m, 64);
#pragma unroll
        for (int r = 0; r < 4; ++r) l_i[r] = l_i[r] * alpha[r] + rs[r];
#pragma unroll
        for (int dt = 0; dt < 4; ++dt)
#pragma unroll
            for (int r = 0; r < 4; ++r) Oacc[dt][r] *= alpha[r];

        // ---- P (C layout) -> LDS -> A layout; per-wave, no barrier needed ----
#pragma unroll
        for (int nt = 0; nt < 4; ++nt)
#pragma unroll
            for (int r = 0; r < 4; ++r)
                Ps[wave][quad * 4 + r][nt * 16 + l15] = f2bf(Sacc[nt][r]);

        // ---- O += P V ----
#pragma unroll
        for (int ks = 0; ks < 2; ++ks) {
            short8 pf = *(const short8*)&Ps[wave][l15][ks * 32 + quad * 8];
#pragma unroll
            for (int dt = 0; dt < 4; ++dt) {
                int d = dt * 16 + l15;
                int col = (((ks * 4 + quad) ^ (d >> 3)) << 3);
                short8 vf = *(const short8*)&Vt[d][col];
                Oacc[dt] = __builtin_amdgcn_mfma_f32_16x16x32_bf16(pf, vf, Oacc[dt], 0, 0, 0);
            }
        }
    }

    // ---- epilogue: O / l, write Y[b,t,h*64+d] ----
    float inv[4];
#pragma unroll
    for (int r = 0; r < 4; ++r) inv[r] = 1.f / l_i[r];
#pragma unroll
    for (int dt = 0; dt < 4; ++dt)
#pragma unroll
        for (int r = 0; r < 4; ++r) {
            int t = qw + quad * 4 + r;
            int d = dt * 16 + l15;
            Y[((size_t)b * TT + t) * CC + h * DD + d] = f2bf(Oacc[dt][r] * inv[r]);
        }
}

// ---------------- launch ----------------
extern "C" void kernel_launch(void* const* d_in, const int* in_sizes, int n_in,
                              void* d_out, int out_size, void* d_ws, size_t ws_size,
                              hipStream_t stream) {
    const float* x      = (const float*)d_in[0];
    // d_in[1] = attn_mask (bool) — mask structure is analytic, unused
    const float* qkv_w  = (const float*)d_in[2];
    const float* qkv_b  = (const float*)d_in[3];
    const float* proj_w = (const float*)d_in[4];
    const float* proj_b = (const float*)d_in[5];
    float* out = (float*)d_out;

    u16* xb  = (u16*)d_ws;                         // 8192*1024
    u16* wb  = xb  + (size_t)8192 * 1024;          // 3072*1024
    u16* pwb = wb  + (size_t)3072 * 1024;          // 1024*1024
    u16* Qb  = pwb + (size_t)1024 * 1024;          // 64*2048*64
    u16* Kb  = Qb  + (size_t)64 * 2048 * 64;
    u16* Vb  = Kb  + (size_t)64 * 2048 * 64;
    u16* Yb  = Vb  + (size_t)64 * 2048 * 64;       // 8192*1024

    cvt_f32_bf16<<<4096, 256, 0, stream>>>(x, xb, 8192 * 1024);
    cvt_f32_bf16<<<1536, 256, 0, stream>>>(qkv_w, wb, 3072 * 1024);
    cvt_f32_bf16<<<512, 256, 0, stream>>>(proj_w, pwb, 1024 * 1024);

    gemm_qkv<<<dim3(24, 64), 256, 0, stream>>>(xb, wb, qkv_b, Qb, Kb, Vb);
    attn_mfma<<<dim3(TT / 64, BB * HH), 256, 0, stream>>>(Qb, Kb, Vb, Yb);
    gemm_proj<<<dim3(8, 64), 256, 0, stream>>>(Yb, pwb, proj_b, out);
}

// Round 3
// 238.289 us; speedup vs baseline: 2.4310x; 1.1474x over previous
//
#include <hip/hip_runtime.h>

#define BB 4
#define TT 2048
#define CC 1024
#define HH 16
#define DD 64
#define WIN 256

typedef __attribute__((ext_vector_type(8))) short short8;
typedef __attribute__((ext_vector_type(4))) float floatx4;
typedef unsigned short u16;

typedef __attribute__((address_space(3))) void lds_void;
typedef const __attribute__((address_space(1))) void g_void;

__device__ __forceinline__ void gl_lds16(const u16* g, u16* l) {
    // async DMA global->LDS, 16B/lane; LDS dst = wave-uniform base + lane*16
    __builtin_amdgcn_global_load_lds((g_void*)g, (lds_void*)l, 16, 0, 0);
}

__device__ __forceinline__ float bf2f(u16 u) {
    union { unsigned int i; float f; } v; v.i = ((unsigned int)u) << 16; return v.f;
}
__device__ __forceinline__ u16 f2bf(float f) {
    union { float f; unsigned int i; } v; v.f = f;
    unsigned int x = v.i;
    x += ((x >> 16) & 1u) + 0x7FFFu;   // round-to-nearest-even
    return (u16)(x >> 16);
}

// ---------------- fp32 -> bf16 conversion (all three arrays, one launch) -----
__global__ void cvt_all(const float* __restrict__ x, const float* __restrict__ qw,
                        const float* __restrict__ pw,
                        u16* __restrict__ xb, u16* __restrict__ wb, u16* __restrict__ pwb) {
    int bid = blockIdx.x;
    const float* src; u16* dst; int off;
    if (bid < 4096)      { src = x;  dst = xb;  off = bid; }
    else if (bid < 5632) { src = qw; dst = wb;  off = bid - 4096; }
    else                 { src = pw; dst = pwb; off = bid - 5632; }
    int i = (off * 256 + (int)threadIdx.x) * 8;
    float4 a = *(const float4*)(src + i);
    float4 b = *(const float4*)(src + i + 4);
    u16 o[8] = { f2bf(a.x), f2bf(a.y), f2bf(a.z), f2bf(a.w),
                 f2bf(b.x), f2bf(b.y), f2bf(b.z), f2bf(b.w) };
    *(uint4*)(dst + i) = *(const uint4*)o;
}

// LDS tile layout (A and B identical), 128 rows x 32 cols bf16, BK=32:
//   8 segments of 1024B; segment s = rows s*16..s*16+15.
//   chunk (row, c) [16B, k-cols c*8..c*8+7] stored at within-seg byte offset
//   (row&15)*64 + (c ^ ((row>>1)&3))*16.  DMA lane L of segment writes L*16;
//   it therefore loads global chunk c = (L&3) ^ ((L>>3)&3), row = seg*16+(L>>2).
//   Fragment ds_read_b128: per 8 consecutive lanes banks {0,16,4,20,8,24,12,28}
//   -> conflict-free.

// ---------------- bf16 MFMA GEMM: C = A @ B^T (+bias), QKV scatter epilogue ----
__global__ __launch_bounds__(256) void gemm_qkv(
    const u16* __restrict__ A, const u16* __restrict__ Bw,
    const float* __restrict__ bias,
    u16* __restrict__ Qb, u16* __restrict__ Kb, u16* __restrict__ Vb)
{
    const int K = CC;
    __shared__ u16 As[4096];   // 8 KB unpadded, swizzled
    __shared__ u16 Bs[4096];
    const int tid = threadIdx.x;
    const int wave = tid >> 6, lane = tid & 63;
    const int wm = wave >> 1, wn = wave & 1;
    const int quad = lane >> 4, l15 = lane & 15;
    const int bN = blockIdx.x * 128, bM = blockIdx.y * 128;

    // staging addresses: issues it=0,1 -> segments wave, wave+4
    const int srow0 = wave * 16 + (lane >> 2);
    const int srow1 = (wave + 4) * 16 + (lane >> 2);
    const int schunk = ((lane & 3) ^ ((lane >> 3) & 3)) * 8;
    const u16* gA0 = A + (size_t)(bM + srow0) * K + schunk;
    const u16* gA1 = A + (size_t)(bM + srow1) * K + schunk;
    const u16* gB0 = Bw + (size_t)(bN + srow0) * K + schunk;
    const u16* gB1 = Bw + (size_t)(bN + srow1) * K + schunk;
    u16* lA0 = &As[wave * 512];
    u16* lA1 = &As[(wave + 4) * 512];
    u16* lB0 = &Bs[wave * 512];
    u16* lB1 = &Bs[(wave + 4) * 512];

    const int rdoff = l15 * 32 + ((quad ^ ((l15 >> 1) & 3)) * 8);  // u16 units

    floatx4 acc[4][4] = {};

    for (int k0 = 0; k0 < K; k0 += 32) {
        __syncthreads();
        gl_lds16(gA0 + k0, lA0);
        gl_lds16(gA1 + k0, lA1);
        gl_lds16(gB0 + k0, lB0);
        gl_lds16(gB1 + k0, lB1);
        __syncthreads();
        short8 af[4], bf[4];
#pragma unroll
        for (int i = 0; i < 4; ++i) {
            af[i] = *(const short8*)&As[(wm * 4 + i) * 512 + rdoff];
            bf[i] = *(const short8*)&Bs[(wn * 4 + i) * 512 + rdoff];
        }
#pragma unroll
        for (int mi = 0; mi < 4; ++mi)
#pragma unroll
            for (int ni = 0; ni < 4; ++ni)
                acc[mi][ni] = __builtin_amdgcn_mfma_f32_16x16x32_bf16(af[mi], bf[ni], acc[mi][ni], 0, 0, 0);
    }

#pragma unroll
    for (int mi = 0; mi < 4; ++mi)
#pragma unroll
        for (int ni = 0; ni < 4; ++ni) {
            int col = bN + wn * 64 + ni * 16 + l15;          // 0..3071
            float bv = bias[col];
            int which = col >> 10, rem = col & 1023;
            int h = rem >> 6, d = rem & 63;
            u16* dst = which == 0 ? Qb : (which == 1 ? Kb : Vb);
#pragma unroll
            for (int rg = 0; rg < 4; ++rg) {
                int row = bM + wm * 64 + mi * 16 + quad * 4 + rg;  // 0..8191
                int b = row >> 11, t = row & 2047;
                float v = acc[mi][ni][rg] + bv;
                dst[(((size_t)(b * HH + h)) * TT + t) * DD + d] = f2bf(v);
            }
        }
}

// ---------------- bf16 MFMA GEMM: Out = A @ B^T + bias (fp32 out) ------------
__global__ __launch_bounds__(256) void gemm_proj(
    const u16* __restrict__ A, const u16* __restrict__ Bw,
    const float* __restrict__ bias, float* __restrict__ Out)
{
    const int K = CC;
    __shared__ u16 As[4096];
    __shared__ u16 Bs[4096];
    const int tid = threadIdx.x;
    const int wave = tid >> 6, lane = tid & 63;
    const int wm = wave >> 1, wn = wave & 1;
    const int quad = lane >> 4, l15 = lane & 15;
    const int bN = blockIdx.x * 128, bM = blockIdx.y * 128;

    const int srow0 = wave * 16 + (lane >> 2);
    const int srow1 = (wave + 4) * 16 + (lane >> 2);
    const int schunk = ((lane & 3) ^ ((lane >> 3) & 3)) * 8;
    const u16* gA0 = A + (size_t)(bM + srow0) * K + schunk;
    const u16* gA1 = A + (size_t)(bM + srow1) * K + schunk;
    const u16* gB0 = Bw + (size_t)(bN + srow0) * K + schunk;
    const u16* gB1 = Bw + (size_t)(bN + srow1) * K + schunk;
    u16* lA0 = &As[wave * 512];
    u16* lA1 = &As[(wave + 4) * 512];
    u16* lB0 = &Bs[wave * 512];
    u16* lB1 = &Bs[(wave + 4) * 512];

    const int rdoff = l15 * 32 + ((quad ^ ((l15 >> 1) & 3)) * 8);

    floatx4 acc[4][4] = {};

    for (int k0 = 0; k0 < K; k0 += 32) {
        __syncthreads();
        gl_lds16(gA0 + k0, lA0);
        gl_lds16(gA1 + k0, lA1);
        gl_lds16(gB0 + k0, lB0);
        gl_lds16(gB1 + k0, lB1);
        __syncthreads();
        short8 af[4], bf[4];
#pragma unroll
        for (int i = 0; i < 4; ++i) {
            af[i] = *(const short8*)&As[(wm * 4 + i) * 512 + rdoff];
            bf[i] = *(const short8*)&Bs[(wn * 4 + i) * 512 + rdoff];
        }
#pragma unroll
        for (int mi = 0; mi < 4; ++mi)
#pragma unroll
            for (int ni = 0; ni < 4; ++ni)
                acc[mi][ni] = __builtin_amdgcn_mfma_f32_16x16x32_bf16(af[mi], bf[ni], acc[mi][ni], 0, 0, 0);
    }

#pragma unroll
    for (int mi = 0; mi < 4; ++mi)
#pragma unroll
        for (int ni = 0; ni < 4; ++ni) {
            int col = bN + wn * 64 + ni * 16 + l15;
            float bv = bias[col];
#pragma unroll
            for (int rg = 0; rg < 4; ++rg) {
                int row = bM + wm * 64 + mi * 16 + quad * 4 + rg;
                Out[(size_t)row * CC + col] = acc[mi][ni][rg] + bv;
            }
        }
}

// ---------------- flash attention, MFMA (bf16 in, fp32 acc) ------------------
// Q/K/V: [B*H, T, D] bf16.  Y: [B, T, C] bf16 (transposed for proj GEMM)
// Block: 256 threads = 4 waves; 64 queries/block (16/wave); key chunks of 64.
__global__ __launch_bounds__(256) void attn_mfma(
    const u16* __restrict__ Qb, const u16* __restrict__ Kb, const u16* __restrict__ Vb,
    u16* __restrict__ Y)
{
    __shared__ u16 Ks[64][72];        // K chunk, [j][d], +8 pad
    __shared__ u16 Vt[64][72];        // V chunk transposed [d][j], XOR-swizzled j-blocks
    __shared__ u16 Ps[4][16][72];     // per-wave P round-trip buffer [q][j]

    const int tid = threadIdx.x;
    const int wave = tid >> 6, lane = tid & 63;
    const int quad = lane >> 4, l15 = lane & 15;
    const int q0 = blockIdx.x * 64;
    const int bh = blockIdx.y;
    const int b = bh >> 4, h = bh & 15;
    const u16* Qp = Qb + (size_t)bh * TT * DD;
    const u16* Kp = Kb + (size_t)bh * TT * DD;
    const u16* Vp = Vb + (size_t)bh * TT * DD;
    const int qw = q0 + wave * 16;    // this wave's first query

    // Q A-fragments: m=l15 (query), k=quad*8+j (d), 2 k-steps
    short8 qf[2];
    qf[0] = *(const short8*)&Qp[(size_t)(qw + l15) * DD + quad * 8];
    qf[1] = *(const short8*)&Qp[(size_t)(qw + l15) * DD + 32 + quad * 8];

    float m_i[4] = { -1e30f, -1e30f, -1e30f, -1e30f };
    float l_i[4] = { 0.f, 0.f, 0.f, 0.f };
    floatx4 Oacc[4] = {};             // [dtile]; C layout: row=quad*4+reg, col(d)=dt*16+l15

    const int kb = (q0 >= WIN) ? (q0 - WIN) : 0;
    for (int j0 = kb; j0 < q0 + 64; j0 += 64) {
        __syncthreads();
        // stage K chunk [j][d], vectorized
#pragma unroll
        for (int it = 0; it < 2; ++it) {
            int slot = tid + it * 256;
            int j = slot >> 3, c8 = (slot & 7) << 3;
            *(uint4*)&Ks[j][c8] = *(const uint4*)&Kp[(size_t)(j0 + j) * DD + c8];
        }
        // stage V transposed [d][j], swizzle j-block by d>>3 (conflict-free writes)
#pragma unroll
        for (int it = 0; it < 2; ++it) {
            int slot = tid + it * 256;
            int j = slot >> 3, d0 = (slot & 7) << 3;
            uint4 raw = *(const uint4*)&Vp[(size_t)(j0 + j) * DD + d0];
            const u16* u = (const u16*)&raw;
#pragma unroll
            for (int i = 0; i < 8; ++i) {
                int d = d0 + i;
                int col = (((j >> 3) ^ (d >> 3)) << 3) + (j & 7);
                Vt[d][col] = u[i];
            }
        }
        __syncthreads();

        // ---- S = Q K^T (scaled), 4 n-tiles of 16 keys ----
        floatx4 Sacc[4] = {};
#pragma unroll
        for (int nt = 0; nt < 4; ++nt) {
            short8 kf0 = *(const short8*)&Ks[nt * 16 + l15][quad * 8];
            short8 kf1 = *(const short8*)&Ks[nt * 16 + l15][32 + quad * 8];
            Sacc[nt] = __builtin_amdgcn_mfma_f32_16x16x32_bf16(qf[0], kf0, Sacc[nt], 0, 0, 0);
            Sacc[nt] = __builtin_amdgcn_mfma_f32_16x16x32_bf16(qf[1], kf1, Sacc[nt], 0, 0, 0);
        }

        // ---- mask + scale + chunk row-max ----
        float mc[4] = { -1e30f, -1e30f, -1e30f, -1e30f };
#pragma unroll
        for (int nt = 0; nt < 4; ++nt)
#pragma unroll
            for (int r = 0; r < 4; ++r) {
                int q = qw + quad * 4 + r;
                int j = j0 + nt * 16 + l15;
                float s = (j <= q && (q - j) < WIN) ? Sacc[nt][r] * 0.125f : -1e30f;
                Sacc[nt][r] = s;
                mc[r] = fmaxf(mc[r], s);
            }
#pragma unroll
        for (int m = 1; m < 16; m <<= 1)
#pragma unroll
            for (int r = 0; r < 4; ++r) mc[r] = fmaxf(mc[r], __shfl_xor(mc[r], m, 64));

        // ---- online softmax update ----
        float alpha[4];
#pragma unroll
        for (int r = 0; r < 4; ++r) {
            float mn = fmaxf(m_i[r], mc[r]);
            alpha[r] = __expf(m_i[r] - mn);
            m_i[r] = mn;
        }
        float rs[4] = { 0.f, 0.f, 0.f, 0.f };
#pragma unroll
        for (int nt = 0; nt < 4; ++nt)
#pragma unroll
            for (int r = 0; r < 4; ++r) {
                float s = Sacc[nt][r];
                float p = (s > -1e29f) ? __expf(s - m_i[r]) : 0.f;
                Sacc[nt][r] = p;
                rs[r] += p;
            }
#pragma unroll
        for (int m = 1; m < 16; m <<= 1)
#pragma unroll
            for (int r = 0; r < 4; ++r) rs[r] += __shfl_xor(rs[r], m, 64);
#pragma unroll
        for (int r = 0; r < 4; ++r) l_i[r] = l_i[r] * alpha[r] + rs[r];
#pragma unroll
        for (int dt = 0; dt < 4; ++dt)
#pragma unroll
            for (int r = 0; r < 4; ++r) Oacc[dt][r] *= alpha[r];

        // ---- P (C layout) -> LDS -> A layout; per-wave, no barrier needed ----
#pragma unroll
        for (int nt = 0; nt < 4; ++nt)
#pragma unroll
            for (int r = 0; r < 4; ++r)
                Ps[wave][quad * 4 + r][nt * 16 + l15] = f2bf(Sacc[nt][r]);

        // ---- O += P V ----
#pragma unroll
        for (int ks = 0; ks < 2; ++ks) {
            short8 pf = *(const short8*)&Ps[wave][l15][ks * 32 + quad * 8];
#pragma unroll
            for (int dt = 0; dt < 4; ++dt) {
                int d = dt * 16 + l15;
                int col = (((ks * 4 + quad) ^ (d >> 3)) << 3);
                short8 vf = *(const short8*)&Vt[d][col];
                Oacc[dt] = __builtin_amdgcn_mfma_f32_16x16x32_bf16(pf, vf, Oacc[dt], 0, 0, 0);
            }
        }
    }

    // ---- epilogue: O / l, write Y[b,t,h*64+d] ----
    float inv[4];
#pragma unroll
    for (int r = 0; r < 4; ++r) inv[r] = 1.f / l_i[r];
#pragma unroll
    for (int dt = 0; dt < 4; ++dt)
#pragma unroll
        for (int r = 0; r < 4; ++r) {
            int t = qw + quad * 4 + r;
            int d = dt * 16 + l15;
            Y[((size_t)b * TT + t) * CC + h * DD + d] = f2bf(Oacc[dt][r] * inv[r]);
        }
}

// ---------------- launch ----------------
extern "C" void kernel_launch(void* const* d_in, const int* in_sizes, int n_in,
                              void* d_out, int out_size, void* d_ws, size_t ws_size,
                              hipStream_t stream) {
    const float* x      = (const float*)d_in[0];
    // d_in[1] = attn_mask (bool) — mask structure is analytic, unused
    const float* qkv_w  = (const float*)d_in[2];
    const float* qkv_b  = (const float*)d_in[3];
    const float* proj_w = (const float*)d_in[4];
    const float* proj_b = (const float*)d_in[5];
    float* out = (float*)d_out;

    u16* xb  = (u16*)d_ws;                         // 8192*1024
    u16* wb  = xb  + (size_t)8192 * 1024;          // 3072*1024
    u16* pwb = wb  + (size_t)3072 * 1024;          // 1024*1024
    u16* Qb  = pwb + (size_t)1024 * 1024;          // 64*2048*64
    u16* Kb  = Qb  + (size_t)64 * 2048 * 64;
    u16* Vb  = Kb  + (size_t)64 * 2048 * 64;
    u16* Yb  = Vb  + (size_t)64 * 2048 * 64;       // 8192*1024

    cvt_all<<<6144, 256, 0, stream>>>(x, qkv_w, proj_w, xb, wb, pwb);
    gemm_qkv<<<dim3(24, 64), 256, 0, stream>>>(xb, wb, qkv_b, Qb, Kb, Vb);
    attn_mfma<<<dim3(TT / 64, BB * HH), 256, 0, stream>>>(Qb, Kb, Vb, Yb);
    gemm_proj<<<dim3(8, 64), 256, 0, stream>>>(Yb, pwb, proj_b, out);
}